// Round 1
// baseline (46.522 us; speedup 1.0000x reference)
//
#include <hip/hip_runtime.h>
#include <stdint.h>
#include <math.h>

#define NLVL 16
#define NPTS 131072

struct Meta {
  int       scales[NLVL];
  long long offsets[NLVL];
  unsigned int T;
  int       start_hash;
  double    invT;
};

// h < 2^38, T ~ 2^19. (double)h is exact; q off by at most +-1, fixed up.
__device__ __forceinline__ long long fastmod(uint64_t h, unsigned int T, double invT) {
  uint64_t q = (uint64_t)((double)h * invT);
  long long r = (long long)(h - q * (uint64_t)T);
  if (r < 0) r += (long long)T;
  else if (r >= (long long)T) r -= (long long)T;
  return r;
}

__global__ __launch_bounds__(256) void hashgrid_fwd(
    const float* __restrict__ xyz,
    const float* __restrict__ wb,
    const float* __restrict__ data,
    float* __restrict__ out,
    Meta meta)
{
#pragma clang fp contract(off)
  const int tid = blockIdx.x * 256 + threadIdx.x;
  const int n = tid >> 4;
  const int l = tid & 15;

  const float bx0 = wb[0], by0 = wb[1], bz0 = wb[2];
  const float bx1 = wb[3], by1 = wb[4], bz1 = wb[5];
  const float denom = fmaxf(fmaxf(bx1 - bx0, by1 - by0), bz1 - bz0) + 1e-6f;

  float px = xyz[3 * n + 0], py = xyz[3 * n + 1], pz = xyz[3 * n + 2];
  px = fminf(fmaxf(px, bx0), bx1);
  py = fminf(fmaxf(py, by0), by1);
  pz = fminf(fmaxf(pz, bz0), bz1);
  const float xn = (px - bx0) / denom;
  const float yn = (py - by0) / denom;
  const float zn = (pz - bz0) / denom;

  const float sf = (float)meta.scales[l];
  const float fx = xn * sf, fy = yn * sf, fz = zn * sf;
  // Corner indices: each is a separate f32 add then trunc, matching
  // (fx + corner).astype(int64) in the reference exactly.
  const int ix0 = (int)fx,          iy0 = (int)fy,          iz0 = (int)fz;
  const int ix1 = (int)(fx + 1.0f), iy1 = (int)(fy + 1.0f), iz1 = (int)(fz + 1.0f);
  const float ox = fx - (float)ix0, oy = fy - (float)iy0, oz = fz - (float)iz0;

  long long idxs[8];
  if (l < meta.start_hash) {
    const long long sp1 = (long long)(meta.scales[l] + 1);
    const long long sq  = sp1 * sp1;
    const long long ax0 = (long long)ix0 * sq,  ax1 = (long long)ix1 * sq;
    const long long ay0 = (long long)iy0 * sp1, ay1 = (long long)iy1 * sp1;
    idxs[0] = ax0 + ay0 + iz0;
    idxs[1] = ax0 + ay0 + iz1;
    idxs[2] = ax0 + ay1 + iz0;
    idxs[3] = ax0 + ay1 + iz1;
    idxs[4] = ax1 + ay0 + iz0;
    idxs[5] = ax1 + ay0 + iz1;
    idxs[6] = ax1 + ay1 + iz0;
    idxs[7] = ax1 + ay1 + iz1;
  } else {
    const uint64_t hx0 = (uint64_t)ix0;
    const uint64_t hx1 = (uint64_t)ix1;
    const uint64_t hy0 = (uint64_t)iy0 * 19349663ull;
    const uint64_t hy1 = (uint64_t)iy1 * 19349663ull;
    const uint64_t hz0 = (uint64_t)iz0 * 83492791ull;
    const uint64_t hz1 = (uint64_t)iz1 * 83492791ull;
    idxs[0] = fastmod(hx0 ^ hy0 ^ hz0, meta.T, meta.invT);
    idxs[1] = fastmod(hx0 ^ hy0 ^ hz1, meta.T, meta.invT);
    idxs[2] = fastmod(hx0 ^ hy1 ^ hz0, meta.T, meta.invT);
    idxs[3] = fastmod(hx0 ^ hy1 ^ hz1, meta.T, meta.invT);
    idxs[4] = fastmod(hx1 ^ hy0 ^ hz0, meta.T, meta.invT);
    idxs[5] = fastmod(hx1 ^ hy0 ^ hz1, meta.T, meta.invT);
    idxs[6] = fastmod(hx1 ^ hy1 ^ hz0, meta.T, meta.invT);
    idxs[7] = fastmod(hx1 ^ hy1 ^ hz1, meta.T, meta.invT);
  }

  const float wx[2] = {1.0f - ox, ox};
  const float wy[2] = {1.0f - oy, oy};
  const float wz[2] = {1.0f - oz, oz};

  const long long base = meta.offsets[l];
  const float2* __restrict__ dp = (const float2*)data;

  float2 v[8];
#pragma unroll
  for (int c = 0; c < 8; ++c) v[c] = dp[base + idxs[c]];

  float acc0 = 0.0f, acc1 = 0.0f;
#pragma unroll
  for (int c = 0; c < 8; ++c) {
    const float w = (wx[(c >> 2) & 1] * wy[(c >> 1) & 1]) * wz[c & 1];
    acc0 += w * v[c].x;
    acc1 += w * v[c].y;
  }

  reinterpret_cast<float2*>(out)[tid] = make_float2(acc0, acc1);
}

static bool isprime_ll(long long v) {
  if (v < 2) return false;
  for (long long i = 2; i * i <= v; ++i)
    if (v % i == 0) return false;
  return true;
}

extern "C" void kernel_launch(void* const* d_in, const int* in_sizes, int n_in,
                              void* d_out, int out_size, void* d_ws, size_t ws_size,
                              hipStream_t stream) {
  (void)in_sizes; (void)n_in; (void)d_ws; (void)ws_size; (void)out_size;

  Meta m;
  long long T = 1LL << 19;
  while (!isprime_ll(T)) ++T;
  const double b = pow(2048.0 / 16.0, 1.0 / 15.0);
  long long off = 0;
  int sh = -1;
  for (int i = 0; i < NLVL; ++i) {
    const int res = (int)(16.0 * pow(b, (double)i));   // matches int(16 * b**i)
    m.scales[i] = res;
    m.offsets[i] = off;
    long long nn = (long long)(res + 1) * (res + 1) * (res + 1);
    if (nn > T) { if (sh < 0) sh = i; nn = T; }
    off += nn;
  }
  m.T = (unsigned int)T;
  m.start_hash = (sh < 0) ? NLVL : sh;
  m.invT = 1.0 / (double)T;

  const float* xyz  = (const float*)d_in[0];
  const float* wbp  = (const float*)d_in[1];
  const float* data = (const float*)d_in[2];
  float* out = (float*)d_out;

  const int total = NPTS * NLVL;
  hipLaunchKernelGGL(hashgrid_fwd, dim3(total / 256), dim3(256), 0, stream,
                     xyz, wbp, data, out, m);
}

// Round 2
// 40.381 us; speedup vs baseline: 1.1521x; 1.1521x over previous
//
#include <hip/hip_runtime.h>
#include <stdint.h>
#include <math.h>

#define NLVL 16
#define NPTS 131072

struct Meta {
  int scales[NLVL];
  int offsets[NLVL];      // element offsets (fit easily in int32: ~6.1M)
  unsigned int T;
  int start_hash;
  double invT;
};

// h < 2^38, T ~ 2^19. (double)h is exact; q off by at most +-1, fixed up.
__device__ __forceinline__ int fastmod(uint64_t h, unsigned int T, double invT) {
  uint64_t q = (uint64_t)((double)h * invT);
  long long r = (long long)(h - q * (uint64_t)T);
  if (r < 0) r += (long long)T;
  else if (r >= (long long)T) r -= (long long)T;
  return (int)r;
}

// Compute the 8 corner indices (with level offset folded in) and fractional
// offsets for one level. Bit-matches the fp32 reference:
//   corner index = (int)(fx + corner_f32), off = fx - (float)ix0.
__device__ __forceinline__ void level_idx(
    int l, float xn, float yn, float zn, const Meta& m,
    int* __restrict__ idx, float* __restrict__ o)
{
#pragma clang fp contract(off)
  const float sf = (float)m.scales[l];
  const float fx = xn * sf, fy = yn * sf, fz = zn * sf;
  const int ix0 = (int)fx,          iy0 = (int)fy,          iz0 = (int)fz;
  const int ix1 = (int)(fx + 1.0f), iy1 = (int)(fy + 1.0f), iz1 = (int)(fz + 1.0f);
  o[0] = fx - (float)ix0; o[1] = fy - (float)iy0; o[2] = fz - (float)iz0;
  const int base = m.offsets[l];

  if (l < m.start_hash) {
    const int sp1 = m.scales[l] + 1;
    const int sq  = sp1 * sp1;
    const int ax0 = ix0 * sq,  ax1 = ix1 * sq;
    const int ay0 = iy0 * sp1, ay1 = iy1 * sp1;
    idx[0] = base + ax0 + ay0 + iz0;
    idx[1] = base + ax0 + ay0 + iz1;
    idx[2] = base + ax0 + ay1 + iz0;
    idx[3] = base + ax0 + ay1 + iz1;
    idx[4] = base + ax1 + ay0 + iz0;
    idx[5] = base + ax1 + ay0 + iz1;
    idx[6] = base + ax1 + ay1 + iz0;
    idx[7] = base + ax1 + ay1 + iz1;
  } else {
    const uint64_t hx0 = (uint64_t)ix0;
    const uint64_t hx1 = (uint64_t)ix1;          // = hx0 + 1
    const uint64_t hy0 = (uint64_t)iy0 * 19349663ull;
    const uint64_t hy1 = hy0 + 19349663ull;      // iy1 == iy0 + 1 always
    const uint64_t hz0 = (uint64_t)iz0 * 83492791ull;
    const uint64_t hz1 = hz0 + 83492791ull;
    idx[0] = base + fastmod(hx0 ^ hy0 ^ hz0, m.T, m.invT);
    idx[1] = base + fastmod(hx0 ^ hy0 ^ hz1, m.T, m.invT);
    idx[2] = base + fastmod(hx0 ^ hy1 ^ hz0, m.T, m.invT);
    idx[3] = base + fastmod(hx0 ^ hy1 ^ hz1, m.T, m.invT);
    idx[4] = base + fastmod(hx1 ^ hy0 ^ hz0, m.T, m.invT);
    idx[5] = base + fastmod(hx1 ^ hy0 ^ hz1, m.T, m.invT);
    idx[6] = base + fastmod(hx1 ^ hy1 ^ hz0, m.T, m.invT);
    idx[7] = base + fastmod(hx1 ^ hy1 ^ hz1, m.T, m.invT);
  }
}

__device__ __forceinline__ void accum8(
    const float2* __restrict__ v, const float* __restrict__ o,
    float& a0, float& a1)
{
#pragma clang fp contract(off)
  const float wx[2] = {1.0f - o[0], o[0]};
  const float wy[2] = {1.0f - o[1], o[1]};
  const float wz[2] = {1.0f - o[2], o[2]};
  a0 = 0.0f; a1 = 0.0f;
#pragma unroll
  for (int c = 0; c < 8; ++c) {
    const float w = (wx[(c >> 2) & 1] * wy[(c >> 1) & 1]) * wz[c & 1];
    a0 += w * v[c].x;
    a1 += w * v[c].y;
  }
}

// Block = 256 threads = 32 points x 8 level-pairs.
// Compute lanes: h = tid>>5 (level pair), p = tid&31  -> wave halves level-uniform.
// Store lanes:   p2 = tid>>3, h2 = tid&7              -> fully coalesced float4.
__global__ __launch_bounds__(256) void hashgrid_fwd(
    const float* __restrict__ xyz,
    const float* __restrict__ wb,
    const float* __restrict__ data,
    float* __restrict__ out,
    Meta meta)
{
#pragma clang fp contract(off)
  const int c    = threadIdx.x;
  const int hc   = c >> 5;
  const int pc   = c & 31;
  const int base = blockIdx.x * 32;

  __shared__ float sxyz[96];
  if (c < 96) sxyz[c] = xyz[base * 3 + c];
  __syncthreads();

  const float bx0 = wb[0], by0 = wb[1], bz0 = wb[2];
  const float bx1 = wb[3], by1 = wb[4], bz1 = wb[5];
  const float denom = fmaxf(fmaxf(bx1 - bx0, by1 - by0), bz1 - bz0) + 1e-6f;

  float px = sxyz[pc * 3 + 0], py = sxyz[pc * 3 + 1], pz = sxyz[pc * 3 + 2];
  px = fminf(fmaxf(px, bx0), bx1);
  py = fminf(fmaxf(py, by0), by1);
  pz = fminf(fmaxf(pz, bz0), bz1);
  const float xn = (px - bx0) / denom;
  const float yn = (py - by0) / denom;
  const float zn = (pz - bz0) / denom;

  const int lA = hc * 2, lB = hc * 2 + 1;
  int idxA[8], idxB[8];
  float oA[3], oB[3];
  level_idx(lA, xn, yn, zn, meta, idxA, oA);
  level_idx(lB, xn, yn, zn, meta, idxB, oB);

  const float2* __restrict__ dp = (const float2*)data;
  float2 vA[8], vB[8];
#pragma unroll
  for (int k = 0; k < 8; ++k) vA[k] = dp[idxA[k]];
#pragma unroll
  for (int k = 0; k < 8; ++k) vB[k] = dp[idxB[k]];

  float4 r;
  accum8(vA, oA, r.x, r.y);
  accum8(vB, oB, r.z, r.w);

  __shared__ float4 lds[32][9];   // pad to 9 to spread banks
  lds[pc][hc] = r;
  __syncthreads();

  const int p2 = c >> 3, h2 = c & 7;
  const float4 v = lds[p2][h2];
  reinterpret_cast<float4*>(out)[(base + p2) * 8 + h2] = v;
}

static bool isprime_ll(long long v) {
  if (v < 2) return false;
  for (long long i = 2; i * i <= v; ++i)
    if (v % i == 0) return false;
  return true;
}

extern "C" void kernel_launch(void* const* d_in, const int* in_sizes, int n_in,
                              void* d_out, int out_size, void* d_ws, size_t ws_size,
                              hipStream_t stream) {
  (void)in_sizes; (void)n_in; (void)d_ws; (void)ws_size; (void)out_size;

  Meta m;
  long long T = 1LL << 19;
  while (!isprime_ll(T)) ++T;
  const double b = pow(2048.0 / 16.0, 1.0 / 15.0);
  long long off = 0;
  int sh = -1;
  for (int i = 0; i < NLVL; ++i) {
    const int res = (int)(16.0 * pow(b, (double)i));   // matches int(16 * b**i)
    m.scales[i] = res;
    m.offsets[i] = (int)off;
    long long nn = (long long)(res + 1) * (res + 1) * (res + 1);
    if (nn > T) { if (sh < 0) sh = i; nn = T; }
    off += nn;
  }
  m.T = (unsigned int)T;
  m.start_hash = (sh < 0) ? NLVL : sh;
  m.invT = 1.0 / (double)T;

  const float* xyz  = (const float*)d_in[0];
  const float* wbp  = (const float*)d_in[1];
  const float* data = (const float*)d_in[2];
  float* out = (float*)d_out;

  hipLaunchKernelGGL(hashgrid_fwd, dim3(NPTS / 32), dim3(256), 0, stream,
                     xyz, wbp, data, out, m);
}